// Round 1
// 632.075 us; speedup vs baseline: 1.7407x; 1.7407x over previous
//
#include <hip/hip_runtime.h>
#include <math.h>

#define N_NODES 100000
#define B 20000
#define DIVIDE 8

typedef __attribute__((ext_vector_type(8))) short bf16x8;
typedef __attribute__((ext_vector_type(4))) float f32x4;

// ws byte offsets
#define BPS_BYTES (16 * 32 * 64 * 16)        // 512 KB  (steps weights)
#define BPF_BYTES (24 * 64 * 64 * 16)        // 1.5 MB  (final fused weights)
#define BIAS_S_BYTE (BPS_BYTES + BPF_BYTES)
#define BIAS_F_BYTE (BIAS_S_BYTE + 512 * 4)

__device__ __forceinline__ float fsigmoid(float x) {
    x = fminf(fmaxf(x, -30.f), 30.f);
    return 1.f / (1.f + __expf(-x));
}
__device__ __forceinline__ float ftanh(float x) {
    x = fminf(fmaxf(x, -15.f), 15.f);
    float e = __expf(2.f * x);
    return (e - 1.f) / (e + 1.f);
}
__device__ __forceinline__ short f2bf(float v) {   // RNE float->bf16 bits
    unsigned u = __builtin_bit_cast(unsigned, v);
    u += 0x7FFFu + ((u >> 16) & 1u);
    return (short)(u >> 16);
}
__device__ __forceinline__ bf16x8 cvt8(float4 a, float4 b) {
    bf16x8 r;
    r[0] = f2bf(a.x); r[1] = f2bf(a.y); r[2] = f2bf(a.z); r[3] = f2bf(a.w);
    r[4] = f2bf(b.x); r[5] = f2bf(b.y); r[6] = f2bf(b.z); r[7] = f2bf(b.w);
    return r;
}

// ---------------- weight prep: b-fragment-major bf16 (unchanged layouts) ----------------
// Bp entry (ks, ct, lane): 8 bf16 = W'[k0+j][c], k0 = ks*32+(lane>>4)*8,
// c = ct*16+(lane&15).  mfma b-frag: B[k][n], n=lane&15, k=(lane>>4)*8+j.

__global__ void prep_bps(const float* __restrict__ Wc, const float* __restrict__ Wcb,
                         const float* __restrict__ Wh, const float* __restrict__ Whb,
                         short* __restrict__ bps, float* __restrict__ bias) {
    int idx = blockIdx.x * 256 + threadIdx.x;    // 16*32*64 = 32768
    int ks = idx >> 11;
    int ct = (idx >> 6) & 31;
    int lane = idx & 63;
    int k0 = ks * 32 + ((lane >> 4) << 3);
    int c = ct * 16 + (lane & 15);
    int j = c & 255;
    bool isH = c >= 256;
    bf16x8 o;
#pragma unroll
    for (int t = 0; t < 8; t++) {
        int k = k0 + t;
        float v;
        if (k < 256) v = Wc[(size_t)(isH ? 256 + j : j) * 256 + k];
        else         v = Wh[(size_t)(isH ? 768 + j : 256 + j) * 256 + (k - 256)];
        o[t] = f2bf(v);
    }
    *(bf16x8*)(bps + (size_t)idx * 8) = o;
    if (idx < 512) {
        float b = (idx < 256) ? (Wcb[idx] + Whb[256 + idx])
                              : (Wcb[256 + (idx - 256)] + Whb[768 + (idx - 256)]);
        bias[idx] = b;
    }
}

__global__ void prep_bpf(const float* __restrict__ Wc, const float* __restrict__ Wcb,
                         const float* __restrict__ Wd, const float* __restrict__ Wdb,
                         const float* __restrict__ Wh, const float* __restrict__ Whb,
                         short* __restrict__ bpf, float* __restrict__ bias) {
    int idx = blockIdx.x * 256 + threadIdx.x;    // 24*64*64 = 98304
    int ks = idx >> 12;
    int ct = (idx >> 6) & 63;
    int lane = idx & 63;
    int k0 = ks * 32 + ((lane >> 4) << 3);
    int c = ct * 16 + (lane & 15);
    int sel = c >> 8, j = c & 255;
    bf16x8 o;
#pragma unroll
    for (int t = 0; t < 8; t++) {
        int k = k0 + t;
        float v = 0.f;
        if (k < 256) {
            if (sel == 0) v = Wc[(size_t)j * 256 + k];
            else if (sel == 1) v = Wc[(size_t)(256 + j) * 256 + k];
        } else if (k < 512) {
            int kk = k - 256;
            int row = (sel == 0) ? (256 + j) : (sel == 1) ? (768 + j)
                    : (sel == 2) ? j : (512 + j);
            v = Wh[(size_t)row * 256 + kk];
        } else {
            int kk = k - 512;
            if (sel == 2) v = Wd[(size_t)j * 256 + kk];
            else if (sel == 3) v = Wd[(size_t)(256 + j) * 256 + kk];
        }
        o[t] = f2bf(v);
    }
    *(bf16x8*)(bpf + (size_t)idx * 8) = o;
    if (idx < 1024) {
        int jj = idx & 255, s = idx >> 8;
        float b = (s == 0) ? (Wcb[jj] + Whb[256 + jj])
                : (s == 1) ? (Wcb[256 + jj] + Whb[768 + jj])
                : (s == 2) ? (Wdb[jj] + Whb[jj])
                           : (Wdb[256 + jj] + Whb[512 + jj]);
        bias[idx] = b;
    }
}

// ---------------- steps 0..6: block = 32 rows x 512 outcols, 8 waves ----------------
// A (msg||gathered mem) staged once per block into LDS as bf16, XOR-swizzled.
// Wave q owns out cols [q*32, q*32+32): 2 gate tiles + 2 h tiles, 2 row tiles.
__global__ __launch_bounds__(512, 4) void step_mfma(
        float* __restrict__ mem, const float* __restrict__ msg,
        const int* __restrict__ ids,
        const bf16x8* __restrict__ Bp, const float* __restrict__ bias) {
    __shared__ int sIds[32];
    __shared__ short As[32 * 512];   // 32 KB: [row][k] bf16, byte ^= (row&7)<<4
    int tid = threadIdx.x;
    int r0 = blockIdx.x * 32;        // B % 32 == 0: no tail
    if (tid < 32) sIds[tid] = ids[r0 + tid];
    __syncthreads();

    // ---- stage: 2048 units of 8 floats; batched loads -> cvt -> ds_write ----
    float4 v0[4], v1[4];
    int gb[4];
#pragma unroll
    for (int j = 0; j < 4; j++) {
        int u = j * 512 + tid;
        int row = u >> 6;            // 64 units per row
        int k0 = (u & 63) * 8;       // k index in [0,512)
        const float* src = (k0 < 256)
            ? msg + (size_t)(r0 + row) * 256 + k0
            : mem + (size_t)sIds[row] * 256 + (k0 - 256);
        v0[j] = *(const float4*)src;
        v1[j] = *(const float4*)(src + 4);
        gb[j] = (row * 1024 + k0 * 2) ^ ((row & 7) << 4);
    }
#pragma unroll
    for (int j = 0; j < 4; j++)
        *(bf16x8*)((char*)As + gb[j]) = cvt8(v0[j], v1[j]);
    __syncthreads();

    int lane = tid & 63, q = tid >> 6;          // q in [0,8)
    int cl = lane & 15, quad = lane >> 4;

    f32x4 accG[2][2] = {{{0.f}}};
    f32x4 accH[2][2] = {{{0.f}}};
    const bf16x8* bp = Bp + lane;

#pragma unroll
    for (int ks = 0; ks < 16; ks++) {
        bf16x8 a[2];
#pragma unroll
        for (int rt = 0; rt < 2; rt++) {
            int row = rt * 16 + cl;
            int ab = (row * 1024 + ks * 64 + quad * 16) ^ ((row & 7) << 4);
            a[rt] = *(const bf16x8*)((const char*)As + ab);
        }
        int base = ks * 32 * 64;
#pragma unroll
        for (int t = 0; t < 2; t++) {
            bf16x8 bg = bp[base + (q * 2 + t) * 64];
            bf16x8 bh = bp[base + (16 + q * 2 + t) * 64];
#pragma unroll
            for (int rt = 0; rt < 2; rt++) {
                accG[rt][t] = __builtin_amdgcn_mfma_f32_16x16x32_bf16(a[rt], bg, accG[rt][t], 0, 0, 0);
                accH[rt][t] = __builtin_amdgcn_mfma_f32_16x16x32_bf16(a[rt], bh, accH[rt][t], 0, 0, 0);
            }
        }
    }
    // no barrier needed: all global reads of mem happened before the staging
    // barrier; each (row,col) is written by exactly one lane grid-wide.

#pragma unroll
    for (int t = 0; t < 2; t++) {
        int col = q * 32 + t * 16 + cl;
        float bg = bias[col], bh = bias[256 + col];
#pragma unroll
        for (int rt = 0; rt < 2; rt++) {
#pragma unroll
            for (int r = 0; r < 4; r++) {
                int id = sIds[rt * 16 + quad * 4 + r];
                float* p = mem + (size_t)id * 256 + col;
                float m = *p;
                float g = fsigmoid(accG[rt][t][r] + bg);
                float h = ftanh(accH[rt][t][r] + bh);
                *p = (1.f - g) * h + g * m;
            }
        }
    }
}

// ---------------- final fused step: block = 32 rows x 1024 outcols, 8 waves ----------------
__global__ __launch_bounds__(512, 4) void final_mfma(
        float* __restrict__ mem, const float* __restrict__ msg,
        const int* __restrict__ ids, const float* __restrict__ dtdg,
        const bf16x8* __restrict__ Bp, const float* __restrict__ bias) {
    __shared__ int sIds[32];
    __shared__ short As[32 * 768];   // 48 KB: [row][k] bf16, row stride 1536 B
    int tid = threadIdx.x;
    int r0 = blockIdx.x * 32;
    if (tid < 32) sIds[tid] = ids[r0 + tid];
    __syncthreads();

    // ---- stage: 3072 units (msg || mem || dtdg) ----
    float4 v0[6], v1[6];
    int gb[6];
#pragma unroll
    for (int j = 0; j < 6; j++) {
        int u = j * 512 + tid;
        int row = u / 96;            // 96 units per row
        int k0 = (u % 96) * 8;       // k index in [0,768)
        const float* src;
        if (k0 < 256)      src = msg + (size_t)(r0 + row) * 256 + k0;
        else if (k0 < 512) src = mem + (size_t)sIds[row] * 256 + (k0 - 256);
        else               src = dtdg + (size_t)sIds[row] * 256 + (k0 - 512);
        v0[j] = *(const float4*)src;
        v1[j] = *(const float4*)(src + 4);
        gb[j] = (row * 1536 + k0 * 2) ^ ((row & 7) << 4);
    }
#pragma unroll
    for (int j = 0; j < 6; j++)
        *(bf16x8*)((char*)As + gb[j]) = cvt8(v0[j], v1[j]);
    __syncthreads();

    int lane = tid & 63, q = tid >> 6;          // q in [0,8)
    int cl = lane & 15, quad = lane >> 4;

    f32x4 aGC[2][2] = {{{0.f}}}, aHC[2][2] = {{{0.f}}};
    f32x4 aGD[2][2] = {{{0.f}}}, aHD[2][2] = {{{0.f}}};
    const bf16x8* bp = Bp + lane;

    // ks 0..7: msg k -> GC,HC ; 8..15: mem k -> all four ; 16..23: dtdg k -> GD,HD
#pragma unroll
    for (int ks = 0; ks < 24; ks++) {
        bf16x8 a[2];
#pragma unroll
        for (int rt = 0; rt < 2; rt++) {
            int row = rt * 16 + cl;
            int ab = (row * 1536 + ks * 64 + quad * 16) ^ ((row & 7) << 4);
            a[rt] = *(const bf16x8*)((const char*)As + ab);
        }
        int base = ks * 64 * 64;
#pragma unroll
        for (int t = 0; t < 2; t++) {
            int ctb = 2 * q + t;
            if (ks < 16) {
                bf16x8 b0 = bp[base + ctb * 64];
                bf16x8 b1 = bp[base + (16 + ctb) * 64];
#pragma unroll
                for (int rt = 0; rt < 2; rt++) {
                    aGC[rt][t] = __builtin_amdgcn_mfma_f32_16x16x32_bf16(a[rt], b0, aGC[rt][t], 0, 0, 0);
                    aHC[rt][t] = __builtin_amdgcn_mfma_f32_16x16x32_bf16(a[rt], b1, aHC[rt][t], 0, 0, 0);
                }
            }
            if (ks >= 8) {
                bf16x8 b2 = bp[base + (32 + ctb) * 64];
                bf16x8 b3 = bp[base + (48 + ctb) * 64];
#pragma unroll
                for (int rt = 0; rt < 2; rt++) {
                    aGD[rt][t] = __builtin_amdgcn_mfma_f32_16x16x32_bf16(a[rt], b2, aGD[rt][t], 0, 0, 0);
                    aHD[rt][t] = __builtin_amdgcn_mfma_f32_16x16x32_bf16(a[rt], b3, aHD[rt][t], 0, 0, 0);
                }
            }
        }
    }

#pragma unroll
    for (int t = 0; t < 2; t++) {
        int col = q * 32 + t * 16 + cl;
        float b0 = bias[col], b1 = bias[256 + col];
        float b2 = bias[512 + col], b3 = bias[768 + col];
#pragma unroll
        for (int rt = 0; rt < 2; rt++) {
#pragma unroll
            for (int r = 0; r < 4; r++) {
                int id = sIds[rt * 16 + quad * 4 + r];
                float* p = mem + (size_t)id * 256 + col;
                float m = *p;
                float gc = fsigmoid(aGC[rt][t][r] + b0);
                float hc = ftanh(aHC[rt][t][r] + b1);
                float gd = fsigmoid(aGD[rt][t][r] + b2);
                float hd = ftanh(aHD[rt][t][r] + b3);
                *p = m + 0.5f * (gc * (hc - m) + gd * (hd - m));
            }
        }
    }
}

extern "C" void kernel_launch(void* const* d_in, const int* in_sizes, int n_in,
                              void* d_out, int out_size, void* d_ws, size_t ws_size,
                              hipStream_t stream) {
    (void)in_sizes; (void)n_in; (void)out_size; (void)ws_size;
    const float* memory = (const float*)d_in[0];
    const int* node_ids = (const int*)d_in[1];
    const float* messages = (const float*)d_in[2];
    const float* dtdg = (const float*)d_in[3];
    const float* Wc = (const float*)d_in[4];
    const float* Wcb = (const float*)d_in[5];
    const float* Wd = (const float*)d_in[6];
    const float* Wdb = (const float*)d_in[7];
    const float* Wh = (const float*)d_in[8];
    const float* Whb = (const float*)d_in[9];
    float* mem = (float*)d_out;
    char* ws = (char*)d_ws;

    short* bps = (short*)ws;
    short* bpf = (short*)(ws + BPS_BYTES);
    float* bias_s = (float*)(ws + BIAS_S_BYTE);
    float* bias_f = (float*)(ws + BIAS_F_BYTE);

    hipMemcpyAsync(mem, memory, (size_t)N_NODES * 256 * sizeof(float),
                   hipMemcpyDeviceToDevice, stream);

    prep_bps<<<128, 256, 0, stream>>>(Wc, Wcb, Wh, Whb, bps, bias_s);
    prep_bpf<<<384, 256, 0, stream>>>(Wc, Wcb, Wd, Wdb, Wh, Whb, bpf, bias_f);

    for (int t = 0; t < DIVIDE - 1; t++) {
        step_mfma<<<B / 32, 512, 0, stream>>>(
            mem, messages + (size_t)t * B * 256, node_ids + (size_t)t * B,
            (const bf16x8*)bps, bias_s);
    }
    final_mfma<<<B / 32, 512, 0, stream>>>(
        mem, messages + (size_t)(DIVIDE - 1) * B * 256,
        node_ids + (size_t)(DIVIDE - 1) * B, dtdg,
        (const bf16x8*)bpf, bias_f);
}

// Round 2
// 629.067 us; speedup vs baseline: 1.7490x; 1.0048x over previous
//
#include <hip/hip_runtime.h>
#include <math.h>

#define N_NODES 100000
#define B 20000
#define DIVIDE 8
#define NTILES (B / 32)                   // 625 step tiles
#define NCOPYBLK ((N_NODES + 63) / 64)    // 1563 copy blocks (step 0 only)

typedef __attribute__((ext_vector_type(8))) short bf16x8;
typedef __attribute__((ext_vector_type(4))) float f32x4;

// ws byte offsets
#define BPS_BYTES (16 * 32 * 64 * 16)        // 512 KB  (steps weights)
#define BPF_BYTES (24 * 64 * 64 * 16)        // 1.5 MB  (final fused weights)
#define BIAS_S_BYTE (BPS_BYTES + BPF_BYTES)
#define BIAS_F_BYTE (BIAS_S_BYTE + 512 * 4)
#define FLAGS_BYTE  (BIAS_F_BYTE + 4096)

__device__ __forceinline__ float fsigmoid(float x) {
    x = fminf(fmaxf(x, -30.f), 30.f);
    return 1.f / (1.f + __expf(-x));
}
__device__ __forceinline__ float ftanh(float x) {
    x = fminf(fmaxf(x, -15.f), 15.f);
    float e = __expf(2.f * x);
    return (e - 1.f) / (e + 1.f);
}
__device__ __forceinline__ short f2bf(float v) {   // RNE float->bf16 bits
    unsigned u = __builtin_bit_cast(unsigned, v);
    u += 0x7FFFu + ((u >> 16) & 1u);
    return (short)(u >> 16);
}
__device__ __forceinline__ bf16x8 cvt8(float4 a, float4 b) {
    bf16x8 r;
    r[0] = f2bf(a.x); r[1] = f2bf(a.y); r[2] = f2bf(a.z); r[3] = f2bf(a.w);
    r[4] = f2bf(b.x); r[5] = f2bf(b.y); r[6] = f2bf(b.z); r[7] = f2bf(b.w);
    return r;
}

// ---------------- weight prep: b-fragment-major bf16 (unchanged layouts) ----------------
__global__ void prep_bps(const float* __restrict__ Wc, const float* __restrict__ Wcb,
                         const float* __restrict__ Wh, const float* __restrict__ Whb,
                         short* __restrict__ bps, float* __restrict__ bias) {
    int idx = blockIdx.x * 256 + threadIdx.x;    // 16*32*64 = 32768
    int ks = idx >> 11;
    int ct = (idx >> 6) & 31;
    int lane = idx & 63;
    int k0 = ks * 32 + ((lane >> 4) << 3);
    int c = ct * 16 + (lane & 15);
    int j = c & 255;
    bool isH = c >= 256;
    bf16x8 o;
#pragma unroll
    for (int t = 0; t < 8; t++) {
        int k = k0 + t;
        float v;
        if (k < 256) v = Wc[(size_t)(isH ? 256 + j : j) * 256 + k];
        else         v = Wh[(size_t)(isH ? 768 + j : 256 + j) * 256 + (k - 256)];
        o[t] = f2bf(v);
    }
    *(bf16x8*)(bps + (size_t)idx * 8) = o;
    if (idx < 512) {
        float b = (idx < 256) ? (Wcb[idx] + Whb[256 + idx])
                              : (Wcb[256 + (idx - 256)] + Whb[768 + (idx - 256)]);
        bias[idx] = b;
    }
}

__global__ void prep_bpf(const float* __restrict__ Wc, const float* __restrict__ Wcb,
                         const float* __restrict__ Wd, const float* __restrict__ Wdb,
                         const float* __restrict__ Wh, const float* __restrict__ Whb,
                         short* __restrict__ bpf, float* __restrict__ bias) {
    int idx = blockIdx.x * 256 + threadIdx.x;    // 24*64*64 = 98304
    int ks = idx >> 12;
    int ct = (idx >> 6) & 63;
    int lane = idx & 63;
    int k0 = ks * 32 + ((lane >> 4) << 3);
    int c = ct * 16 + (lane & 15);
    int sel = c >> 8, j = c & 255;
    bf16x8 o;
#pragma unroll
    for (int t = 0; t < 8; t++) {
        int k = k0 + t;
        float v = 0.f;
        if (k < 256) {
            if (sel == 0) v = Wc[(size_t)j * 256 + k];
            else if (sel == 1) v = Wc[(size_t)(256 + j) * 256 + k];
        } else if (k < 512) {
            int kk = k - 256;
            int row = (sel == 0) ? (256 + j) : (sel == 1) ? (768 + j)
                    : (sel == 2) ? j : (512 + j);
            v = Wh[(size_t)row * 256 + kk];
        } else {
            int kk = k - 512;
            if (sel == 2) v = Wd[(size_t)j * 256 + kk];
            else if (sel == 3) v = Wd[(size_t)(256 + j) * 256 + kk];
        }
        o[t] = f2bf(v);
    }
    *(bf16x8*)(bpf + (size_t)idx * 8) = o;
    if (idx < 1024) {
        int jj = idx & 255, s = idx >> 8;
        float b = (s == 0) ? (Wcb[jj] + Whb[256 + jj])
                : (s == 1) ? (Wcb[256 + jj] + Whb[768 + jj])
                : (s == 2) ? (Wdb[jj] + Whb[jj])
                           : (Wdb[256 + jj] + Whb[512 + jj]);
        bias[idx] = b;
    }
}

// mark rows written by step 0 (copy blocks skip them)
__global__ void set_flags(const int* __restrict__ ids, unsigned char* __restrict__ flags) {
    int i = blockIdx.x * 256 + threadIdx.x;
    if (i < B) flags[ids[i]] = 1;
}

// ---------------- step kernel: 32 rows x 512 outcols, 8 waves ----------------
// blocks >= NTILES (step 0 launch only): masked copy memory->mem of untouched rows.
// Pipelined: msg loads -> gathers issued -> msg half compute (gathers in flight)
// -> land gathers + prefetch epilogue m -> mem half compute -> store-only epilogue.
__global__ __launch_bounds__(512, 4) void step_fused(
        const float* __restrict__ gsrc, float* __restrict__ mem,
        const float* __restrict__ msg, const int* __restrict__ ids,
        const bf16x8* __restrict__ Bp, const float* __restrict__ bias,
        const float* __restrict__ msrc, const unsigned char* __restrict__ flags) {
    int tid = threadIdx.x;
    if (blockIdx.x >= NTILES) {              // copy role (step 0 only)
        int row = (blockIdx.x - NTILES) * 64 + (tid >> 3);
        if (row < N_NODES && !flags[row]) {
            const float4* s = (const float4*)(msrc + (size_t)row * 256);
            float4* d = (float4*)(mem + (size_t)row * 256);
            int c0 = tid & 7;
#pragma unroll
            for (int j = 0; j < 8; j++) d[c0 + j * 8] = s[c0 + j * 8];
        }
        return;
    }
    __shared__ int sIds[32];
    __shared__ short As[32 * 512];   // 32 KB: [row][k] bf16, byte ^= (row&7)<<4
    int r0 = blockIdx.x * 32;
    if (tid < 32) sIds[tid] = ids[r0 + tid];
    __syncthreads();

    // msg loads FIRST (their vmcnt wait must not drain the gathers)
    float4 a0[2], a1[2]; int ab_[2];
#pragma unroll
    for (int j = 0; j < 2; j++) {
        int i = j * 512 + tid;
        int row = i >> 5, k0 = (i & 31) * 8;
        const float* s = msg + (size_t)(r0 + row) * 256 + k0;
        a0[j] = *(const float4*)s; a1[j] = *(const float4*)(s + 4);
        ab_[j] = (row * 1024 + k0 * 2) ^ ((row & 7) << 4);
    }
    // scattered mem-row gathers: stay in flight across the msg-half compute
    float4 g0[2], g1[2]; int gb_[2];
#pragma unroll
    for (int j = 0; j < 2; j++) {
        int i = j * 512 + tid;
        int row = i >> 5, k = (i & 31) * 8;
        const float* s = gsrc + (size_t)sIds[row] * 256 + k;
        g0[j] = *(const float4*)s; g1[j] = *(const float4*)(s + 4);
        gb_[j] = (row * 1024 + 512 + k * 2) ^ ((row & 7) << 4);
    }
#pragma unroll
    for (int j = 0; j < 2; j++)
        *(bf16x8*)((char*)As + ab_[j]) = cvt8(a0[j], a1[j]);
    __syncthreads();

    int lane = tid & 63, q = tid >> 6;
    int cl = lane & 15, quad = lane >> 4;

    f32x4 accG[2][2] = {{{0.f}}};
    f32x4 accH[2][2] = {{{0.f}}};
    const bf16x8* bp = Bp + lane;

#pragma unroll
    for (int ks = 0; ks < 8; ks++) {         // msg half
        bf16x8 a[2];
#pragma unroll
        for (int rt = 0; rt < 2; rt++) {
            int row = rt * 16 + cl;
            int ab = (row * 1024 + ks * 64 + quad * 16) ^ ((row & 7) << 4);
            a[rt] = *(const bf16x8*)((const char*)As + ab);
        }
        int base = ks * 32 * 64;
#pragma unroll
        for (int t = 0; t < 2; t++) {
            bf16x8 bg = bp[base + (q * 2 + t) * 64];
            bf16x8 bh = bp[base + (16 + q * 2 + t) * 64];
#pragma unroll
            for (int rt = 0; rt < 2; rt++) {
                accG[rt][t] = __builtin_amdgcn_mfma_f32_16x16x32_bf16(a[rt], bg, accG[rt][t], 0, 0, 0);
                accH[rt][t] = __builtin_amdgcn_mfma_f32_16x16x32_bf16(a[rt], bh, accH[rt][t], 0, 0, 0);
            }
        }
    }
    // land the gathers into the mem-half of As (disjoint region, no pre-barrier)
#pragma unroll
    for (int j = 0; j < 2; j++)
        *(bf16x8*)((char*)As + gb_[j]) = cvt8(g0[j], g1[j]);
    // prefetch epilogue m (pre-update values) -- hides under the mem-half loop
    float mpre[2][2][4];
#pragma unroll
    for (int t = 0; t < 2; t++)
#pragma unroll
        for (int rt = 0; rt < 2; rt++)
#pragma unroll
            for (int r = 0; r < 4; r++)
                mpre[t][rt][r] = gsrc[(size_t)sIds[rt * 16 + quad * 4 + r] * 256
                                      + q * 32 + t * 16 + cl];
    __syncthreads();

#pragma unroll
    for (int ks = 8; ks < 16; ks++) {        // mem half
        bf16x8 a[2];
#pragma unroll
        for (int rt = 0; rt < 2; rt++) {
            int row = rt * 16 + cl;
            int ab = (row * 1024 + ks * 64 + quad * 16) ^ ((row & 7) << 4);
            a[rt] = *(const bf16x8*)((const char*)As + ab);
        }
        int base = ks * 32 * 64;
#pragma unroll
        for (int t = 0; t < 2; t++) {
            bf16x8 bg = bp[base + (q * 2 + t) * 64];
            bf16x8 bh = bp[base + (16 + q * 2 + t) * 64];
#pragma unroll
            for (int rt = 0; rt < 2; rt++) {
                accG[rt][t] = __builtin_amdgcn_mfma_f32_16x16x32_bf16(a[rt], bg, accG[rt][t], 0, 0, 0);
                accH[rt][t] = __builtin_amdgcn_mfma_f32_16x16x32_bf16(a[rt], bh, accH[rt][t], 0, 0, 0);
            }
        }
    }

    // store-only epilogue
#pragma unroll
    for (int t = 0; t < 2; t++) {
        int col = q * 32 + t * 16 + cl;
        float bg = bias[col], bh = bias[256 + col];
#pragma unroll
        for (int rt = 0; rt < 2; rt++) {
#pragma unroll
            for (int r = 0; r < 4; r++) {
                int id = sIds[rt * 16 + quad * 4 + r];
                float m = mpre[t][rt][r];
                float g = fsigmoid(accG[rt][t][r] + bg);
                float h = ftanh(accH[rt][t][r] + bh);
                mem[(size_t)id * 256 + col] = (1.f - g) * h + g * m;
            }
        }
    }
}

// ---------------- final fused step: 32 rows x 1024 outcols, 8 waves ----------------
__global__ __launch_bounds__(512, 4) void final_mfma(
        float* __restrict__ mem, const float* __restrict__ msg,
        const int* __restrict__ ids, const float* __restrict__ dtdg,
        const bf16x8* __restrict__ Bp, const float* __restrict__ bias) {
    __shared__ int sIds[32];
    __shared__ short As[32 * 768];   // 48 KB: [row][k] bf16, row stride 1536 B
    int tid = threadIdx.x;
    int r0 = blockIdx.x * 32;
    if (tid < 32) sIds[tid] = ids[r0 + tid];
    __syncthreads();

    // msg loads first, then mem gathers (in flight across msg-half compute)
    float4 a0[2], a1[2]; int ab_[2];
#pragma unroll
    for (int j = 0; j < 2; j++) {
        int i = j * 512 + tid;
        int row = i >> 5, k0 = (i & 31) * 8;
        const float* s = msg + (size_t)(r0 + row) * 256 + k0;
        a0[j] = *(const float4*)s; a1[j] = *(const float4*)(s + 4);
        ab_[j] = (row * 1536 + k0 * 2) ^ ((row & 7) << 4);
    }
    float4 g0[2], g1[2]; int gb_[2];
#pragma unroll
    for (int j = 0; j < 2; j++) {
        int i = j * 512 + tid;
        int row = i >> 5, k = (i & 31) * 8;
        const float* s = mem + (size_t)sIds[row] * 256 + k;
        g0[j] = *(const float4*)s; g1[j] = *(const float4*)(s + 4);
        gb_[j] = (row * 1536 + 512 + k * 2) ^ ((row & 7) << 4);
    }
#pragma unroll
    for (int j = 0; j < 2; j++)
        *(bf16x8*)((char*)As + ab_[j]) = cvt8(a0[j], a1[j]);
    __syncthreads();

    int lane = tid & 63, q = tid >> 6;
    int cl = lane & 15, quad = lane >> 4;

    f32x4 aGC[2][2] = {{{0.f}}}, aHC[2][2] = {{{0.f}}};
    f32x4 aGD[2][2] = {{{0.f}}}, aHD[2][2] = {{{0.f}}};
    const bf16x8* bp = Bp + lane;

#pragma unroll
    for (int ks = 0; ks < 8; ks++) {          // msg k -> GC,HC
        bf16x8 a[2];
#pragma unroll
        for (int rt = 0; rt < 2; rt++) {
            int row = rt * 16 + cl;
            int ab = (row * 1536 + ks * 64 + quad * 16) ^ ((row & 7) << 4);
            a[rt] = *(const bf16x8*)((const char*)As + ab);
        }
        int base = ks * 64 * 64;
#pragma unroll
        for (int t = 0; t < 2; t++) {
            int ctb = 2 * q + t;
            bf16x8 b0 = bp[base + ctb * 64];
            bf16x8 b1 = bp[base + (16 + ctb) * 64];
#pragma unroll
            for (int rt = 0; rt < 2; rt++) {
                aGC[rt][t] = __builtin_amdgcn_mfma_f32_16x16x32_bf16(a[rt], b0, aGC[rt][t], 0, 0, 0);
                aHC[rt][t] = __builtin_amdgcn_mfma_f32_16x16x32_bf16(a[rt], b1, aHC[rt][t], 0, 0, 0);
            }
        }
    }
    // land mem gathers; prefetch epilogue m
#pragma unroll
    for (int j = 0; j < 2; j++)
        *(bf16x8*)((char*)As + gb_[j]) = cvt8(g0[j], g1[j]);
    float mpre[2][2][4];
#pragma unroll
    for (int t = 0; t < 2; t++)
#pragma unroll
        for (int rt = 0; rt < 2; rt++)
#pragma unroll
            for (int r = 0; r < 4; r++)
                mpre[t][rt][r] = mem[(size_t)sIds[rt * 16 + quad * 4 + r] * 256
                                     + q * 32 + t * 16 + cl];
    __syncthreads();

#pragma unroll
    for (int ks = 8; ks < 16; ks++) {         // mem k -> all four
        bf16x8 a[2];
#pragma unroll
        for (int rt = 0; rt < 2; rt++) {
            int row = rt * 16 + cl;
            int ab = (row * 1536 + ks * 64 + quad * 16) ^ ((row & 7) << 4);
            a[rt] = *(const bf16x8*)((const char*)As + ab);
        }
        int base = ks * 64 * 64;
#pragma unroll
        for (int t = 0; t < 2; t++) {
            int ctb = 2 * q + t;
            bf16x8 b0 = bp[base + ctb * 64];
            bf16x8 b1 = bp[base + (16 + ctb) * 64];
            bf16x8 b2 = bp[base + (32 + ctb) * 64];
            bf16x8 b3 = bp[base + (48 + ctb) * 64];
#pragma unroll
            for (int rt = 0; rt < 2; rt++) {
                aGC[rt][t] = __builtin_amdgcn_mfma_f32_16x16x32_bf16(a[rt], b0, aGC[rt][t], 0, 0, 0);
                aHC[rt][t] = __builtin_amdgcn_mfma_f32_16x16x32_bf16(a[rt], b1, aHC[rt][t], 0, 0, 0);
                aGD[rt][t] = __builtin_amdgcn_mfma_f32_16x16x32_bf16(a[rt], b2, aGD[rt][t], 0, 0, 0);
                aHD[rt][t] = __builtin_amdgcn_mfma_f32_16x16x32_bf16(a[rt], b3, aHD[rt][t], 0, 0, 0);
            }
        }
    }

    // dtdg stage (short exposure, one kernel only)
    float4 d0[2], d1[2]; int db_[2];
#pragma unroll
    for (int j = 0; j < 2; j++) {
        int i = j * 512 + tid;
        int row = i >> 5, k = (i & 31) * 8;
        const float* s = dtdg + (size_t)sIds[row] * 256 + k;
        d0[j] = *(const float4*)s; d1[j] = *(const float4*)(s + 4);
        db_[j] = (row * 1536 + 1024 + k * 2) ^ ((row & 7) << 4);
    }
#pragma unroll
    for (int j = 0; j < 2; j++)
        *(bf16x8*)((char*)As + db_[j]) = cvt8(d0[j], d1[j]);
    __syncthreads();

#pragma unroll
    for (int ks = 16; ks < 24; ks++) {        // dtdg k -> GD,HD
        bf16x8 a[2];
#pragma unroll
        for (int rt = 0; rt < 2; rt++) {
            int row = rt * 16 + cl;
            int ab = (row * 1536 + ks * 64 + quad * 16) ^ ((row & 7) << 4);
            a[rt] = *(const bf16x8*)((const char*)As + ab);
        }
        int base = ks * 64 * 64;
#pragma unroll
        for (int t = 0; t < 2; t++) {
            int ctb = 2 * q + t;
            bf16x8 b2 = bp[base + (32 + ctb) * 64];
            bf16x8 b3 = bp[base + (48 + ctb) * 64];
#pragma unroll
            for (int rt = 0; rt < 2; rt++) {
                aGD[rt][t] = __builtin_amdgcn_mfma_f32_16x16x32_bf16(a[rt], b2, aGD[rt][t], 0, 0, 0);
                aHD[rt][t] = __builtin_amdgcn_mfma_f32_16x16x32_bf16(a[rt], b3, aHD[rt][t], 0, 0, 0);
            }
        }
    }

#pragma unroll
    for (int t = 0; t < 2; t++) {
        int col = q * 32 + t * 16 + cl;
        float b0 = bias[col], b1 = bias[256 + col];
        float b2 = bias[512 + col], b3 = bias[768 + col];
#pragma unroll
        for (int rt = 0; rt < 2; rt++) {
#pragma unroll
            for (int r = 0; r < 4; r++) {
                int id = sIds[rt * 16 + quad * 4 + r];
                float m = mpre[t][rt][r];
                float gc = fsigmoid(aGC[rt][t][r] + b0);
                float hc = ftanh(aHC[rt][t][r] + b1);
                float gd = fsigmoid(aGD[rt][t][r] + b2);
                float hd = ftanh(aHD[rt][t][r] + b3);
                mem[(size_t)id * 256 + col] = m + 0.5f * (gc * (hc - m) + gd * (hd - m));
            }
        }
    }
}

extern "C" void kernel_launch(void* const* d_in, const int* in_sizes, int n_in,
                              void* d_out, int out_size, void* d_ws, size_t ws_size,
                              hipStream_t stream) {
    (void)in_sizes; (void)n_in; (void)out_size; (void)ws_size;
    const float* memory = (const float*)d_in[0];
    const int* node_ids = (const int*)d_in[1];
    const float* messages = (const float*)d_in[2];
    const float* dtdg = (const float*)d_in[3];
    const float* Wc = (const float*)d_in[4];
    const float* Wcb = (const float*)d_in[5];
    const float* Wd = (const float*)d_in[6];
    const float* Wdb = (const float*)d_in[7];
    const float* Wh = (const float*)d_in[8];
    const float* Whb = (const float*)d_in[9];
    float* mem = (float*)d_out;
    char* ws = (char*)d_ws;

    short* bps = (short*)ws;
    short* bpf = (short*)(ws + BPS_BYTES);
    float* bias_s = (float*)(ws + BIAS_S_BYTE);
    float* bias_f = (float*)(ws + BIAS_F_BYTE);
    unsigned char* flags = (unsigned char*)(ws + FLAGS_BYTE);

    // mark step-0 rows; copy blocks inside step 0 skip them (copy runs
    // concurrent with step-0 compute instead of a serial 102 MB memcpy)
    hipMemsetAsync(flags, 0, N_NODES, stream);
    set_flags<<<(B + 255) / 256, 256, 0, stream>>>(node_ids, flags);

    prep_bps<<<128, 256, 0, stream>>>(Wc, Wcb, Wh, Whb, bps, bias_s);
    prep_bpf<<<384, 256, 0, stream>>>(Wc, Wcb, Wd, Wdb, Wh, Whb, bpf, bias_f);

    // step 0: gathers from input `memory`, fused masked copy of untouched rows
    step_fused<<<NTILES + NCOPYBLK, 512, 0, stream>>>(
        memory, mem, messages, node_ids,
        (const bf16x8*)bps, bias_s, memory, flags);

    for (int t = 1; t < DIVIDE - 1; t++) {
        step_fused<<<NTILES, 512, 0, stream>>>(
            mem, mem, messages + (size_t)t * B * 256, node_ids + (size_t)t * B,
            (const bf16x8*)bps, bias_s, nullptr, nullptr);
    }
    final_mfma<<<NTILES, 512, 0, stream>>>(
        mem, messages + (size_t)(DIVIDE - 1) * B * 256,
        node_ids + (size_t)(DIVIDE - 1) * B, dtdg,
        (const bf16x8*)bpf, bias_f);
}